// Round 2
// baseline (695.677 us; speedup 1.0000x reference)
//
#include <hip/hip_runtime.h>

// Problem: VQ-VAE codebook quantization
//   x: [32, 256, 32, 32] f32  -> z: [N=32768, D=256] (transposed view)
//   W: [1024, 256] f32 codebook (K=1024)
//   idx[n]   = argmin_k ( |z_n|^2 - 2 z_n.W_k + |W_k|^2 )   (first-min tie-break)
//   z_q.flat[n*256+d] = W[idx[n]][d]      (faithful "view" reshape bug)
//   loss = 1.25 * mean((z_q.flat - x.flat)^2)
// Outputs concatenated flat as f32: z_q (8388608), idx-as-float (32768), loss (1)
//
// R2: acc[8][16] (6 LDS reads / 128 FMA, was 4/64), K-tile 512, D-chunk 16,
//     W register-prefetch + z double-buffer gll so both __syncthreads drains are free.

#define N_ROWS 32768
#define K_CODES 1024
#define D_DIM 256

#define ROWS 64    // rows per block
#define KT 512     // codes per k-tile (2 tiles cover K=1024)
#define DT 16      // dims per staged chunk
#define KTP 516    // padded wT row stride (words): %32==4 -> ~2-way write scatter, 16B-aligned reads
#define NDC 16     // d-chunks per k-tile (256/16)

// ---------------- wsq + loss-accumulator zero ----------------
__global__ void wsq_kernel(const float* __restrict__ W, float* __restrict__ wsq,
                           float* __restrict__ loss_acc) {
    int k = blockIdx.x * blockDim.x + threadIdx.x;
    if (k == 0) *loss_acc = 0.0f;
    if (k < K_CODES) {
        const float4* w4 = (const float4*)(W + (size_t)k * D_DIM);
        float s = 0.0f;
#pragma unroll 8
        for (int i = 0; i < D_DIM / 4; i++) {
            float4 v = w4[i];
            s += v.x * v.x + v.y * v.y + v.z * v.z + v.w * v.w;
        }
        wsq[k] = s;
    }
}

// ---------------- fused distance-GEMM + argmin ----------------
// 256 threads: tr = t>>5 (8 row-groups of 8 rows), tc = t&31 (32 code-groups of 16 codes).
// Per thread: acc[8][16]; per d: 2 broadcast zr reads + 4 bank-clean wc reads -> 128 FMA.
__launch_bounds__(256, 2)
__global__ void argmin_kernel(const float* __restrict__ x, const float* __restrict__ W,
                              const float* __restrict__ wsq,
                              float* __restrict__ out_idx_f, int* __restrict__ ws_idx) {
    __shared__ float zT[2][DT][ROWS];   // 8 KB    zT[buf][dloc][r]
    __shared__ float wT[DT][KTP];       // 33 KB   wT[dloc][k] = W[k0+k][d0+dloc]

    const int t    = threadIdx.x;
    const int wv   = t >> 6;       // wave id 0..3 (wave-uniform)
    const int tc   = t & 31;
    const int tr   = t >> 5;
    const int tr8  = tr * 8;
    const int tc4  = tc * 4;

    const int n0  = blockIdx.x * ROWS;
    const int b   = n0 >> 10;          // 1024 rows per batch image (64 | 1024, no straddle)
    const int hw0 = n0 & 1023;
    const size_t xbase = (size_t)b * D_DIM * 1024;

    float rmin[8];
    int   ridx[8];
#pragma unroll
    for (int i = 0; i < 8; i++) { rmin[i] = 1e30f; ridx[i] = 0; }

    float4 wreg[8];   // W chunk prefetch: 512 codes x 16 dims = 2048 float4 / 256 thr

    // --- helpers (inlined by unrolled use) ---
    // z chunk: 16 dims x 64 rows = 256 float4s, one gll per wave, linear LDS dest
#define STAGE_Z(d0_, buf_)                                                              \
    {                                                                                   \
        const float* src_ = x + xbase + ((size_t)((d0_) + (t >> 4)) << 10)              \
                          + hw0 + ((t & 15) << 2);                                      \
        __builtin_amdgcn_global_load_lds(                                               \
            (const __attribute__((address_space(1))) void*)src_,                        \
            (__attribute__((address_space(3))) void*)&zT[buf_][wv << 2][0], 16, 0, 0);  \
    }
#define LOAD_W(k0_, d0_)                                                                \
    _Pragma("unroll")                                                                   \
    for (int i_ = 0; i_ < 8; i_++) {                                                    \
        int e_ = t + i_ * 256;                                                          \
        int kk_ = e_ >> 2, dgq_ = e_ & 3;                                               \
        wreg[i_] = *(const float4*)(W + (size_t)((k0_) + kk_) * D_DIM + (d0_) + dgq_ * 4); \
    }

    // prologue: prefetch chunk 0
    STAGE_Z(0, 0);
    LOAD_W(0, 0);
    int cur = 0;

#pragma unroll 1
    for (int kt = 0; kt < 2; kt++) {
        const int k0 = kt * KT;
        float acc[8][16] = {{0.f}};

#pragma unroll 1
        for (int dc = 0; dc < NDC; dc++) {
            __syncthreads();   // A: prior compute done with wT; z-gll(cur) landed (free drain)
            // ---- write prefetched W regs -> wT (transpose scatter, ~2-way)
#pragma unroll
            for (int i = 0; i < 8; i++) {
                int e = t + i * 256;
                int kk = e >> 2, dgq = e & 3;
                wT[dgq * 4 + 0][kk] = wreg[i].x;
                wT[dgq * 4 + 1][kk] = wreg[i].y;
                wT[dgq * 4 + 2][kk] = wreg[i].z;
                wT[dgq * 4 + 3][kk] = wreg[i].w;
            }
            __syncthreads();   // B: wT visible; no vmem outstanding (free drain)

            // ---- issue next-chunk prefetch; completes under the FMAs below
            const int ch = kt * NDC + dc;
            if (ch != 31) {
                const int ktn = (ch + 1) >> 4, dcn = (ch + 1) & 15;
                STAGE_Z(dcn * DT, cur ^ 1);
                LOAD_W(ktn * KT, dcn * DT);
            }

            // ---- compute: 16 d-steps x 128 FMA
#pragma unroll
            for (int d = 0; d < DT; d++) {
                float zr[8], wc[16];
                *(float4*)&zr[0] = *(const float4*)&zT[cur][d][tr8];
                *(float4*)&zr[4] = *(const float4*)&zT[cur][d][tr8 + 4];
                *(float4*)&wc[0]  = *(const float4*)&wT[d][tc4];
                *(float4*)&wc[4]  = *(const float4*)&wT[d][tc4 + 128];
                *(float4*)&wc[8]  = *(const float4*)&wT[d][tc4 + 256];
                *(float4*)&wc[12] = *(const float4*)&wT[d][tc4 + 384];
#pragma unroll
                for (int i = 0; i < 8; i++)
#pragma unroll
                    for (int q = 0; q < 16; q++)
                        acc[i][q] = fmaf(zr[i], wc[q], acc[i][q]);
            }
            cur ^= 1;
        }

        // ---- score tile kt & update running argmin (k ascending within thread)
#pragma unroll
        for (int g = 0; g < 4; g++)
#pragma unroll
            for (int j = 0; j < 4; j++) {
                int k = k0 + g * 128 + tc4 + j;
                float ws = wsq[k];
#pragma unroll
                for (int i = 0; i < 8; i++) {
                    float s = ws - 2.0f * acc[i][g * 4 + j];
                    if (s < rmin[i]) { rmin[i] = s; ridx[i] = k; }
                }
            }
    }

    // ---- reduce across the 32 tc lanes (same wave; tr pairs share lanes 0-31/32-63)
#pragma unroll
    for (int off = 1; off < 32; off <<= 1) {
#pragma unroll
        for (int i = 0; i < 8; i++) {
            float ov = __shfl_xor(rmin[i], off);
            int   oi = __shfl_xor(ridx[i], off);
            if (ov < rmin[i] || (ov == rmin[i] && oi < ridx[i])) { rmin[i] = ov; ridx[i] = oi; }
        }
    }
    if (tc == 0) {
#pragma unroll
        for (int i = 0; i < 8; i++) {
            int n = n0 + tr8 + i;
            ws_idx[n]    = ridx[i];
            out_idx_f[n] = (float)ridx[i];
        }
    }
#undef STAGE_Z
#undef LOAD_W
}

// ---------------- gather z_q + loss SSE ----------------
__global__ void gather_loss_kernel(const float* __restrict__ x, const float* __restrict__ W,
                                   const int* __restrict__ ws_idx,
                                   float* __restrict__ out_zq, float* __restrict__ loss_acc) {
    __shared__ float red[256];
    const size_t P4 = (size_t)N_ROWS * D_DIM / 4;   // 2097152 float4s
    size_t tid = (size_t)blockIdx.x * blockDim.x + threadIdx.x;
    size_t stride = (size_t)gridDim.x * blockDim.x;
    float acc = 0.0f;
    for (size_t p4 = tid; p4 < P4; p4 += stride) {
        int n = (int)(p4 >> 6);            // 64 float4s per row
        int j = (int)((p4 & 63) << 2);
        int k = ws_idx[n];
        float4 wv = *(const float4*)(W + (size_t)k * D_DIM + j);
        float4 xv = *(const float4*)(x + p4 * 4);
        float dx = wv.x - xv.x, dy = wv.y - xv.y, dz = wv.z - xv.z, dw = wv.w - xv.w;
        acc += dx * dx + dy * dy + dz * dz + dw * dw;
        *(float4*)(out_zq + p4 * 4) = wv;
    }
    red[threadIdx.x] = acc;
    __syncthreads();
    for (int s = 128; s > 0; s >>= 1) {
        if ((int)threadIdx.x < s) red[threadIdx.x] += red[threadIdx.x + s];
        __syncthreads();
    }
    if (threadIdx.x == 0) atomicAdd(loss_acc, red[0]);
}

__global__ void finalize_kernel(const float* __restrict__ loss_acc, float* __restrict__ out_loss) {
    out_loss[0] = 1.25f * loss_acc[0] * (1.0f / 8388608.0f);
}

extern "C" void kernel_launch(void* const* d_in, const int* in_sizes, int n_in,
                              void* d_out, int out_size, void* d_ws, size_t ws_size,
                              hipStream_t stream) {
    const float* x = (const float*)d_in[0];   // 32*256*32*32
    const float* W = (const float*)d_in[1];   // 1024*256

    float* out      = (float*)d_out;
    float* out_zq   = out;                         // 8388608
    float* out_idx  = out + 8388608;               // 32768
    float* out_loss = out + 8388608 + 32768;       // 1

    float* loss_acc = (float*)d_ws;                          // 4 B
    float* wsq      = (float*)((char*)d_ws + 4096);          // 4 KB
    int*   ws_idx   = (int*)((char*)d_ws + 8192);            // 128 KB

    wsq_kernel<<<4, 256, 0, stream>>>(W, wsq, loss_acc);
    argmin_kernel<<<N_ROWS / ROWS, 256, 0, stream>>>(x, W, wsq, out_idx, ws_idx);
    gather_loss_kernel<<<2048, 256, 0, stream>>>(x, W, ws_idx, out_zq, loss_acc);
    finalize_kernel<<<1, 1, 0, stream>>>(loss_acc, out_loss);
}

// Round 3
// 209.375 us; speedup vs baseline: 3.3226x; 3.3226x over previous
//
#include <hip/hip_runtime.h>

// VQ-VAE codebook quantization — R3: MFMA bf16-split distance GEMM.
//   x: [32, 256, 32, 32] f32 -> z: [N=32768, D=256]; W: [1024, 256] f32
//   idx[n] = argmin_k (|w_k|^2 - 2 z_n.w_k)  (|z|^2 constant per row)
//   Exactness: bf16 3-term split error <= ~8e-3 << MARGIN=0.0625; rows with
//   (second-best - best) <= MARGIN are exactly rescored in fp32.
// Outputs flat f32: z_q (8388608), idx-as-float (32768), loss (1)
// Zh/Zl bf16 staged inside out_zq region (33.55 MB, overwritten by gather at end).

#define N_ROWS 32768
#define K_CODES 1024
#define D_DIM 256
#define MARGIN 0.0625f

using f32x4  = __attribute__((ext_vector_type(4))) float;
using bf16x8 = __attribute__((ext_vector_type(8))) short;

__device__ __forceinline__ unsigned int rne_bf16(float f) {
    unsigned int u = __float_as_uint(f);
    return (u + 0x7FFFu + ((u >> 16) & 1u)) >> 16;   // round-to-nearest-even bf16 bits
}

// ---------------- wsq (exact fp32) + accumulator zeroing ----------------
__global__ void wsq_kernel(const float* __restrict__ W, float* __restrict__ wsq,
                           float* __restrict__ loss_acc, int* __restrict__ scount) {
    int k = blockIdx.x * blockDim.x + threadIdx.x;
    if (k == 0) { *loss_acc = 0.0f; *scount = 0; }
    if (k < K_CODES) {
        const float4* w4 = (const float4*)(W + (size_t)k * D_DIM);
        float s = 0.0f;
#pragma unroll 8
        for (int i = 0; i < D_DIM / 4; i++) {
            float4 v = w4[i];
            s += v.x * v.x + v.y * v.y + v.z * v.z + v.w * v.w;
        }
        wsq[k] = s;
    }
}

// ---------------- W -> bf16 hi/lo ----------------
__global__ void convw_kernel(const float* __restrict__ W, unsigned short* __restrict__ Wh,
                             unsigned short* __restrict__ Wl) {
    int p = blockIdx.x * 256 + threadIdx.x;    // 65536 float4s
    float4 v = *(const float4*)(W + (size_t)p * 4);
    unsigned int h0 = rne_bf16(v.x), h1 = rne_bf16(v.y), h2 = rne_bf16(v.z), h3 = rne_bf16(v.w);
    float f0 = __uint_as_float(h0 << 16), f1 = __uint_as_float(h1 << 16);
    float f2 = __uint_as_float(h2 << 16), f3 = __uint_as_float(h3 << 16);
    unsigned int l0 = rne_bf16(v.x - f0), l1 = rne_bf16(v.y - f1);
    unsigned int l2 = rne_bf16(v.z - f2), l3 = rne_bf16(v.w - f3);
    uint2 hp = make_uint2(h0 | (h1 << 16), h2 | (h3 << 16));
    uint2 lp = make_uint2(l0 | (l1 << 16), l2 | (l3 << 16));
    *(uint2*)(Wh + (size_t)p * 4) = hp;
    *(uint2*)(Wl + (size_t)p * 4) = lp;
}

// ---------------- x -> Zh/Zl bf16 [n][d] (transpose via LDS) ----------------
__global__ void convz_kernel(const float* __restrict__ x, unsigned short* __restrict__ Zh,
                             unsigned short* __restrict__ Zl) {
    __shared__ float tile[64][65];
    const int bid = blockIdx.x;            // 2048 = 32 b * 4 dblk * 16 hwblk
    const int b = bid >> 6, dblk = (bid >> 4) & 3, hwblk = bid & 15;
    const int t = threadIdx.x;
    const float* xb = x + ((size_t)(b * 256 + dblk * 64)) * 1024 + hwblk * 64;
#pragma unroll
    for (int i = 0; i < 4; i++) {
        int dl = i * 16 + (t >> 4);
        int hl = (t & 15) * 4;
        float4 v = *(const float4*)(xb + (size_t)dl * 1024 + hl);
        tile[dl][hl] = v.x; tile[dl][hl + 1] = v.y; tile[dl][hl + 2] = v.z; tile[dl][hl + 3] = v.w;
    }
    __syncthreads();
    const int n0 = b * 1024 + hwblk * 64, d0 = dblk * 64;
#pragma unroll
    for (int j = 0; j < 2; j++) {
        int r = j * 32 + (t >> 3);
        int dc = (t & 7) * 8;
        unsigned int hi[8], lo[8];
#pragma unroll
        for (int q = 0; q < 8; q++) {
            float f = tile[dc + q][r];
            hi[q] = rne_bf16(f);
            lo[q] = rne_bf16(f - __uint_as_float(hi[q] << 16));
        }
        uint4 hp = make_uint4(hi[0] | (hi[1] << 16), hi[2] | (hi[3] << 16),
                              hi[4] | (hi[5] << 16), hi[6] | (hi[7] << 16));
        uint4 lp = make_uint4(lo[0] | (lo[1] << 16), lo[2] | (lo[3] << 16),
                              lo[4] | (lo[5] << 16), lo[6] | (lo[7] << 16));
        *(uint4*)(Zh + (size_t)(n0 + r) * 256 + d0 + dc) = hp;
        *(uint4*)(Zl + (size_t)(n0 + r) * 256 + d0 + dc) = lp;
    }
}

// ---------------- MFMA distance GEMM + best/second argmin ----------------
// Block: 128 codes x 128 zrows, K=768 (3 passes x 256), BK=32 (m97 structure).
// 4 waves (2 wm x 2 wn), each 64x64 out = 4x4 frags of 16x16x32 bf16 MFMA.
#define GBM 128
#define GBK 32

__launch_bounds__(256, 3)
__global__ void mm_argmin_kernel(const unsigned short* __restrict__ Zh,
                                 const unsigned short* __restrict__ Zl,
                                 const unsigned short* __restrict__ Wh,
                                 const unsigned short* __restrict__ Wl,
                                 const float* __restrict__ wsq, float* __restrict__ pws) {
    __shared__ unsigned short Al[GBM * GBK];   // 8 KB  [code][k]
    __shared__ unsigned short Bl[GBM * GBK];   // 8 KB  [zrow][k]
    __shared__ float red[2][GBM][3];           // 3 KB

    const int t = threadIdx.x;
    const int w = t >> 6, lane = t & 63;
    const int wm = w & 1, wn = w >> 1;
    const int cb = blockIdx.x & 7;          // code block (8 share one z-tile)
    const int nb = blockIdx.x >> 3;
    const int c0 = cb * GBM, n0 = nb * GBM;

    f32x4 acc[4][4];
#pragma unroll
    for (int i = 0; i < 4; i++)
#pragma unroll
        for (int j = 0; j < 4; j++) acc[i][j] = (f32x4){0.f, 0.f, 0.f, 0.f};

    const int srow = lane >> 2;           // staging: 16 rows / instr, 4 lanes / row
    const int soff = (lane & 3) * 8;      // ushort offset within row
    const int rsel = (lane & 15) * GBK + (lane >> 4) * 8;   // fragment read offset

#pragma unroll 1
    for (int ch = 0; ch < 24; ch++) {
        const int p  = ch >> 3;           // pass: 0 Zh*Wh, 1 Zh*Wl, 2 Zl*Wh
        const int d0 = (ch & 7) * GBK;
        const unsigned short* As = (p == 1) ? Wl : Wh;
        const unsigned short* Bs = (p == 2) ? Zl : Zh;
        __syncthreads();                  // prior reads of Al/Bl done
#pragma unroll
        for (int j = 0; j < 2; j++) {
            int i = w * 2 + j;
            const unsigned short* srcA = As + (size_t)(c0 + i * 16 + srow) * 256 + d0 + soff;
            __builtin_amdgcn_global_load_lds(
                (const __attribute__((address_space(1))) void*)srcA,
                (__attribute__((address_space(3))) void*)(Al + i * 512), 16, 0, 0);
            const unsigned short* srcB = Bs + (size_t)(n0 + i * 16 + srow) * 256 + d0 + soff;
            __builtin_amdgcn_global_load_lds(
                (const __attribute__((address_space(1))) void*)srcB,
                (__attribute__((address_space(3))) void*)(Bl + i * 512), 16, 0, 0);
        }
        __syncthreads();                  // drains vmcnt -> tiles ready

        bf16x8 af[4], bf[4];
#pragma unroll
        for (int mf = 0; mf < 4; mf++)
            af[mf] = *(const bf16x8*)(Al + (wm * 64 + mf * 16) * GBK + rsel);
#pragma unroll
        for (int nf = 0; nf < 4; nf++)
            bf[nf] = *(const bf16x8*)(Bl + (wn * 64 + nf * 16) * GBK + rsel);
#pragma unroll
        for (int mf = 0; mf < 4; mf++)
#pragma unroll
            for (int nf = 0; nf < 4; nf++)
                acc[mf][nf] = __builtin_amdgcn_mfma_f32_16x16x32_bf16(af[mf], bf[nf], acc[mf][nf], 0, 0, 0);
    }

    // ---- epilogue: scores + best/second argmin
    // lane's codes: c0 + wm*64 + mf*16 + (lane>>4)*4 + r ; zrow col = lane&15 (per nf)
    float ws16[16];
#pragma unroll
    for (int mf = 0; mf < 4; mf++)
#pragma unroll
        for (int r = 0; r < 4; r++)
            ws16[mf * 4 + r] = wsq[c0 + wm * 64 + mf * 16 + ((lane >> 4) << 2) + r];

    float b1[4], b2[4]; int i1[4];
#pragma unroll
    for (int nf = 0; nf < 4; nf++) {
        b1[nf] = 1e30f; b2[nf] = 1e30f; i1[nf] = 0;
#pragma unroll
        for (int mf = 0; mf < 4; mf++)
#pragma unroll
            for (int r = 0; r < 4; r++) {
                float s = ws16[mf * 4 + r] - 2.0f * acc[mf][nf][r];
                int code = c0 + wm * 64 + mf * 16 + ((lane >> 4) << 2) + r;
                if (s < b1[nf]) { b2[nf] = b1[nf]; b1[nf] = s; i1[nf] = code; }
                else if (s < b2[nf]) b2[nf] = s;
            }
    }
    // merge across the 4 kblk lane-groups holding the same zrow (lane&15)
#pragma unroll
    for (int off = 16; off <= 32; off <<= 1) {
#pragma unroll
        for (int nf = 0; nf < 4; nf++) {
            float ob1 = __shfl_xor(b1[nf], off);
            float ob2 = __shfl_xor(b2[nf], off);
            int   oi1 = __shfl_xor(i1[nf], off);
            float nb2 = fminf(fminf(b2[nf], ob2), fmaxf(b1[nf], ob1));
            if (ob1 < b1[nf] || (ob1 == b1[nf] && oi1 < i1[nf])) { b1[nf] = ob1; i1[nf] = oi1; }
            b2[nf] = nb2;
        }
    }
    if ((lane >> 4) == 0) {
#pragma unroll
        for (int nf = 0; nf < 4; nf++) {
            int zr = wn * 64 + nf * 16 + (lane & 15);
            red[wm][zr][0] = b1[nf];
            red[wm][zr][1] = __int_as_float(i1[nf]);
            red[wm][zr][2] = b2[nf];
        }
    }
    __syncthreads();
    if (t < GBM) {
        float a1 = red[0][t][0], ai = red[0][t][1], a2 = red[0][t][2];
        float c1 = red[1][t][0], ci = red[1][t][1], c2 = red[1][t][2];
        float m2 = fminf(fminf(a2, c2), fmaxf(a1, c1));
        float m1 = a1, mi = ai;
        if (c1 < a1) { m1 = c1; mi = ci; }   // tie keeps wm0 (lower codes)
        float* dst = pws + ((size_t)(n0 + t) * 8 + cb) * 3;
        dst[0] = m1; dst[1] = mi; dst[2] = m2;
    }
}

// ---------------- combine 8 code-block partials; flag suspects ----------------
__global__ void combine_kernel(const float* __restrict__ pws, float* __restrict__ out_idx_f,
                               int* __restrict__ ws_idx, int* __restrict__ scount,
                               int* __restrict__ slist) {
    int n = blockIdx.x * 256 + threadIdx.x;
    float b1 = 1e30f, bi = 0.f, b2 = 1e30f;
    const float* e = pws + (size_t)n * 24;
#pragma unroll
    for (int cbk = 0; cbk < 8; cbk++) {
        float e1 = e[cbk * 3 + 0], ei = e[cbk * 3 + 1], e2 = e[cbk * 3 + 2];
        float m2 = fminf(fminf(b2, e2), fmaxf(b1, e1));
        if (e1 < b1) { b1 = e1; bi = ei; }   // ties keep earlier cb (lower codes)
        b2 = m2;
    }
    int idx = __float_as_int(bi);
    ws_idx[n] = idx;
    out_idx_f[n] = (float)idx;
    if (b2 - b1 <= MARGIN) {
        int pos = atomicAdd(scount, 1);
        slist[pos] = n;
    }
}

// ---------------- exact fp32 rescore of suspect rows ----------------
__global__ void rescore_kernel(const float* __restrict__ x, const float* __restrict__ W,
                               const float* __restrict__ wsq, const int* __restrict__ scount,
                               const int* __restrict__ slist, float* __restrict__ out_idx_f,
                               int* __restrict__ ws_idx) {
    __shared__ float zrow[256];
    __shared__ float rv[256];
    __shared__ int   ri[256];
    const int cnt = *scount;
    for (int s = blockIdx.x; s < cnt; s += gridDim.x) {
        const int n = slist[s];
        const int b = n >> 10, hw = n & 1023;
        __syncthreads();
        zrow[threadIdx.x] = x[(((size_t)(b * 256 + threadIdx.x)) << 10) + hw];
        __syncthreads();
        float best = 1e30f; int bidx = 0;
        for (int j = 0; j < 4; j++) {
            const int k = threadIdx.x + j * 256;    // ascending per thread
            const float4* wr = (const float4*)(W + (size_t)k * 256);
            float dot = 0.f;
#pragma unroll 16
            for (int q = 0; q < 64; q++) {
                float4 wv = wr[q];
                float4 zv = *(const float4*)&zrow[q * 4];
                dot = fmaf(wv.x, zv.x, dot); dot = fmaf(wv.y, zv.y, dot);
                dot = fmaf(wv.z, zv.z, dot); dot = fmaf(wv.w, zv.w, dot);
            }
            float sc = wsq[k] - 2.f * dot;
            if (sc < best) { best = sc; bidx = k; }
        }
        rv[threadIdx.x] = best; ri[threadIdx.x] = bidx;
        __syncthreads();
        for (int st = 128; st > 0; st >>= 1) {
            if ((int)threadIdx.x < st) {
                float ov = rv[threadIdx.x + st]; int oi = ri[threadIdx.x + st];
                if (ov < rv[threadIdx.x] || (ov == rv[threadIdx.x] && oi < ri[threadIdx.x])) {
                    rv[threadIdx.x] = ov; ri[threadIdx.x] = oi;
                }
            }
            __syncthreads();
        }
        if (threadIdx.x == 0) { ws_idx[n] = ri[0]; out_idx_f[n] = (float)ri[0]; }
    }
}

// ---------------- fallback fp32 argmin (proven R1 kernel, used if ws too small) ----------------
#define FROWS 64
#define FKT 256
#define FDT 32
#define FKTP 260

__launch_bounds__(256, 3)
__global__ void argmin_f32_kernel(const float* __restrict__ x, const float* __restrict__ W,
                                  const float* __restrict__ wsq,
                                  float* __restrict__ out_idx_f, int* __restrict__ ws_idx) {
    __shared__ float zT[FDT][FROWS];
    __shared__ float wT[FDT][FKTP];
    const int t = threadIdx.x;
    const int lane = t & 63;
    const int wv = t >> 6;
    const int tc = t & 31;
    const int tr = t >> 5;
    const int tr8 = tr * 8, tc4 = tc * 4;
    const int n0 = blockIdx.x * FROWS;
    const int b = n0 >> 10;
    const int hw0 = n0 & 1023;
    const size_t xbase = (size_t)b * D_DIM * 1024;
    float rmin[8]; int ridx[8];
#pragma unroll
    for (int i = 0; i < 8; i++) { rmin[i] = 1e30f; ridx[i] = 0; }
#pragma unroll 1
    for (int k0 = 0; k0 < K_CODES; k0 += FKT) {
        float acc[8][8] = {{0.f}};
#pragma unroll 1
        for (int d0 = 0; d0 < D_DIM; d0 += FDT) {
#pragma unroll
            for (int i = 0; i < 2; i++) {
                int dl0 = wv * 8 + i * 4;
                const float* src = x + xbase + ((size_t)(d0 + dl0 + (lane >> 4)) << 10)
                                 + hw0 + ((lane & 15) << 2);
                __builtin_amdgcn_global_load_lds(
                    (const __attribute__((address_space(1))) void*)src,
                    (__attribute__((address_space(3))) void*)&zT[dl0][0], 16, 0, 0);
            }
#pragma unroll
            for (int i = 0; i < 8; i++) {
                int e = t + i * 256;
                int kk = e >> 3, dg = e & 7;
                float4 v = *(const float4*)(W + (size_t)(k0 + kk) * D_DIM + d0 + dg * 4);
                wT[dg * 4 + 0][kk] = v.x; wT[dg * 4 + 1][kk] = v.y;
                wT[dg * 4 + 2][kk] = v.z; wT[dg * 4 + 3][kk] = v.w;
            }
            __syncthreads();
#pragma unroll 4
            for (int d = 0; d < FDT; d++) {
                float zr[8], wc[8];
                *(float4*)&zr[0] = *(const float4*)&zT[d][tr8];
                *(float4*)&zr[4] = *(const float4*)&zT[d][tr8 + 4];
                *(float4*)&wc[0] = *(const float4*)&wT[d][tc4];
                *(float4*)&wc[4] = *(const float4*)&wT[d][tc4 + 128];
#pragma unroll
                for (int i = 0; i < 8; i++)
#pragma unroll
                    for (int j = 0; j < 8; j++)
                        acc[i][j] = fmaf(zr[i], wc[j], acc[i][j]);
            }
            __syncthreads();
        }
#pragma unroll
        for (int g = 0; g < 2; g++)
#pragma unroll
            for (int j = 0; j < 4; j++) {
                int k = k0 + g * 128 + tc4 + j;
                float ws = wsq[k];
#pragma unroll
                for (int i = 0; i < 8; i++) {
                    float s = ws - 2.0f * acc[i][g * 4 + j];
                    if (s < rmin[i]) { rmin[i] = s; ridx[i] = k; }
                }
            }
    }
#pragma unroll
    for (int off = 1; off < 32; off <<= 1) {
#pragma unroll
        for (int i = 0; i < 8; i++) {
            float ov = __shfl_xor(rmin[i], off);
            int oi = __shfl_xor(ridx[i], off);
            if (ov < rmin[i] || (ov == rmin[i] && oi < ridx[i])) { rmin[i] = ov; ridx[i] = oi; }
        }
    }
    if (tc == 0) {
#pragma unroll
        for (int i = 0; i < 8; i++) {
            int n = n0 + tr8 + i;
            ws_idx[n] = ridx[i];
            out_idx_f[n] = (float)ridx[i];
        }
    }
}

// ---------------- gather z_q + loss SSE ----------------
__global__ void gather_loss_kernel(const float* __restrict__ x, const float* __restrict__ W,
                                   const int* __restrict__ ws_idx,
                                   float* __restrict__ out_zq, float* __restrict__ loss_acc) {
    __shared__ float red[256];
    const size_t P4 = (size_t)N_ROWS * D_DIM / 4;
    size_t tid = (size_t)blockIdx.x * blockDim.x + threadIdx.x;
    size_t stride = (size_t)gridDim.x * blockDim.x;
    float acc = 0.0f;
    for (size_t p4 = tid; p4 < P4; p4 += stride) {
        int n = (int)(p4 >> 6);
        int j = (int)((p4 & 63) << 2);
        int k = ws_idx[n];
        float4 wv = *(const float4*)(W + (size_t)k * D_DIM + j);
        float4 xv = *(const float4*)(x + p4 * 4);
        float dx = wv.x - xv.x, dy = wv.y - xv.y, dz = wv.z - xv.z, dw = wv.w - xv.w;
        acc += dx * dx + dy * dy + dz * dz + dw * dw;
        *(float4*)(out_zq + p4 * 4) = wv;
    }
    red[threadIdx.x] = acc;
    __syncthreads();
    for (int s = 128; s > 0; s >>= 1) {
        if ((int)threadIdx.x < s) red[threadIdx.x] += red[threadIdx.x + s];
        __syncthreads();
    }
    if (threadIdx.x == 0) atomicAdd(loss_acc, red[0]);
}

__global__ void finalize_kernel(const float* __restrict__ loss_acc, float* __restrict__ out_loss) {
    out_loss[0] = 1.25f * loss_acc[0] * (1.0f / 8388608.0f);
}

extern "C" void kernel_launch(void* const* d_in, const int* in_sizes, int n_in,
                              void* d_out, int out_size, void* d_ws, size_t ws_size,
                              hipStream_t stream) {
    const float* x = (const float*)d_in[0];
    const float* W = (const float*)d_in[1];

    float* out      = (float*)d_out;
    float* out_zq   = out;                         // 8388608 f32
    float* out_idx  = out + 8388608;               // 32768 f32
    float* out_loss = out + 8388608 + 32768;       // 1 f32

    // workspace layout
    float* loss_acc = (float*)d_ws;                              // @0
    int*   scount   = (int*)((char*)d_ws + 8);                   // @8
    float* wsq      = (float*)((char*)d_ws + 1024);              // 4 KB
    int*   ws_idx   = (int*)((char*)d_ws + 8192);                // 128 KB
    int*   slist    = (int*)((char*)d_ws + 139264);              // 128 KB
    unsigned short* Wh = (unsigned short*)((char*)d_ws + 270336);   // 512 KB
    unsigned short* Wl = (unsigned short*)((char*)d_ws + 794624);   // 512 KB
    float* pws      = (float*)((char*)d_ws + 1318912);           // 3 MB
    const size_t NEEDED = 4464640;

    wsq_kernel<<<4, 256, 0, stream>>>(W, wsq, loss_acc, scount);

    if (ws_size >= NEEDED) {
        // Zh/Zl bf16 live in the out_zq region (exactly 2 x 16.78 MB); gather overwrites later.
        unsigned short* Zh = (unsigned short*)out_zq;
        unsigned short* Zl = Zh + (size_t)N_ROWS * D_DIM;

        convw_kernel<<<256, 256, 0, stream>>>(W, Wh, Wl);
        convz_kernel<<<2048, 256, 0, stream>>>(x, Zh, Zl);
        mm_argmin_kernel<<<2048, 256, 0, stream>>>(Zh, Zl, Wh, Wl, wsq, pws);
        combine_kernel<<<128, 256, 0, stream>>>(pws, out_idx, ws_idx, scount, slist);
        rescore_kernel<<<128, 256, 0, stream>>>(x, W, wsq, scount, slist, out_idx, ws_idx);
    } else {
        argmin_f32_kernel<<<N_ROWS / FROWS, 256, 0, stream>>>(x, W, wsq, out_idx, ws_idx);
    }

    gather_loss_kernel<<<2048, 256, 0, stream>>>(x, W, ws_idx, out_zq, loss_acc);
    finalize_kernel<<<1, 1, 0, stream>>>(loss_acc, out_loss);
}